// Round 5
// baseline (342.804 us; speedup 1.0000x reference)
//
#include <hip/hip_runtime.h>
#include <math.h>

// Quantize/dequantize with 64-level sorted codebook.
// symbols = argmin_j |codebook[j] - (x - means)|  (tie -> lower index)
// y_hat   = codebook[symbols] + means
//
// symbol = #{ mid[j] < r } (strict <, mid = 0.5*(cb[j]+cb[j+1]); matches
// reference tie rule). A 1024-cell uniform LUT over [cb[0], cb[63]]:
// per cell c: epos = {pos = #mids in cells < c, n = #mids in cell c},
//             emid = first mid in cell c (INF if none).
// Query: pos += (emid < r); rare n>1 cells scan s_mid[pos0+1..pos0+n-1].
// cellof() is the identical monotone function at build and query, so
// mids in lower cells are < r and mids in higher cells are > r; output is
// bit-identical to the original binary-search kernel.
//
// Structure lessons (rounds 0-4):
//  - flat grid with quick-retiring blocks drives HBM; grid-stride at 2048
//    blocks does not (2.3 TB/s vs ~4.5).
//  - VALU/LDS are <10% of capacity at the HBM rate; the limiter is the
//    memory system. This round: nontemporal stores so the 201 MB write
//    stream doesn't evict the L3-resident input (FETCH_SIZE was 98 MB of
//    a logical 201 MB -> half the input was being evicted by writes).

#define NCELL 1024

// native vector type for nontemporal stores (HIP float4 is a class type,
// rejected by __builtin_nontemporal_store)
typedef float f32x4 __attribute__((ext_vector_type(4)));

__device__ __forceinline__ int cellof(float v, float lo, float scale) {
    float t = (v - lo) * scale;                 // sub+mul, no fma contraction
    t = fminf(fmaxf(t, 0.0f), (float)(NCELL - 1));
    return (int)t;
}

// ---------------- pre-kernel: build emid[1024], epos[1024], mid[64] --------
__global__ __launch_bounds__(256) void build_lut_kernel(
    const float* __restrict__ codebook,
    float* __restrict__ ws_mid,        // [64] midpoints (+INF sentinel at 63)
    float* __restrict__ ws_emid,       // [NCELL]
    unsigned int* __restrict__ ws_epos)// [NCELL]  pos | (n<<16)
{
    __shared__ float s_cb[64];
    __shared__ float s_mid[64];
    __shared__ unsigned short s_fm[64];

    const int tid = threadIdx.x;
    if (tid < 64) s_cb[tid] = codebook[tid];
    __syncthreads();
    const float lo    = s_cb[0];
    const float range = s_cb[63] - lo;
    const float scale = (range > 0.0f) ? ((float)NCELL / range) : 0.0f;
    if (tid < 64) {
        float mid = (tid < 63) ? 0.5f * (s_cb[tid] + s_cb[tid + 1]) : INFINITY;
        s_mid[tid]  = mid;
        ws_mid[tid] = mid;
        s_fm[tid] = (tid < 63) ? (unsigned short)cellof(mid, lo, scale)
                               : (unsigned short)0xFFFF;  // sentinel >= NCELL
    }
    __syncthreads();

#pragma unroll
    for (int e = 0; e < NCELL / 256; ++e) {
        const int c = tid + e * 256;
        // lower_bound(s_fm[0..62], c): #mids in cells < c (pad never counted)
        int pos = 0;
#pragma unroll
        for (int s = 32; s > 0; s >>= 1)
            pos += (s_fm[pos + s - 1] < c) ? s : 0;
        // lower_bound(s_fm, c+1): #mids in cells <= c
        int pos1 = 0;
#pragma unroll
        for (int s = 32; s > 0; s >>= 1)
            pos1 += (s_fm[pos1 + s - 1] < c + 1) ? s : 0;
        const int n = pos1 - pos;                 // #mids in cell c
        ws_emid[c] = (n > 0) ? s_mid[pos] : INFINITY;
        ws_epos[c] = (unsigned int)pos | ((unsigned int)n << 16);
    }
}

// ---------------- main kernel: flat grid, 2 float4/thread, quick retire ----
__global__ __launch_bounds__(256) void quant_dequant_kernel(
    const float4* __restrict__ x4,
    const float4* __restrict__ m4,
    const float*  __restrict__ codebook,
    const float*  __restrict__ ws_mid,
    const float4* __restrict__ ws_emid4,        // emid as float4[NCELL/4]
    const uint4*  __restrict__ ws_epos4,        // epos as uint4[NCELL/4]
    f32x4* __restrict__ sym_out,
    f32x4* __restrict__ yhat_out,
    int n4)
{
    __shared__ float        s_emid[NCELL];
    __shared__ unsigned int s_epos[NCELL];
    __shared__ float        s_cb[64];
    __shared__ float        s_mid[64];

    const int tid = threadIdx.x;

    // setup loads first (L2/L3-hot, ~8.75 KB per block)
    const float4 ev  = ws_emid4[tid];
    const uint4  pv  = ws_epos4[tid];
    const float  cbv  = (tid < 64) ? codebook[tid] : 0.0f;
    const float  midv = (tid < 64) ? ws_mid[tid]   : 0.0f;

    // payload loads (overlap setup latency)
    const int base = blockIdx.x * 512 + tid;
    const bool full = (blockIdx.x * 512 + 512) <= n4;
    float4 xa, xb, ma, mb;
    if (full) {
        xa = x4[base];       ma = m4[base];
        xb = x4[base + 256]; mb = m4[base + 256];
    } else {
        if (base < n4)       { xa = x4[base];       ma = m4[base]; }
        if (base + 256 < n4) { xb = x4[base + 256]; mb = m4[base + 256]; }
    }

    ((float4*)s_emid)[tid] = ev;
    ((uint4*)s_epos)[tid]  = pv;
    if (tid < 64) { s_cb[tid] = cbv; s_mid[tid] = midv; }
    __syncthreads();

    const float lo    = s_cb[0];
    const float range = s_cb[63] - lo;
    const float scale = (range > 0.0f) ? ((float)NCELL / range) : 0.0f;

    float xr[8] = { xa.x, xa.y, xa.z, xa.w, xb.x, xb.y, xb.z, xb.w };
    float mr[8] = { ma.x, ma.y, ma.z, ma.w, mb.x, mb.y, mb.z, mb.w };
    float sv[8], yv[8];

#pragma unroll
    for (int k = 0; k < 8; ++k) {
        const float m = mr[k];
        const float r = xr[k] - m;
        const int   c = cellof(r, lo, scale);
        const float        emid = s_emid[c];   // independent b32 reads,
        const unsigned int ep   = s_epos[c];   // full 32-bank spread
        const int pos0 = (int)(ep & 0xFFFFu);
        const int n    = (int)(ep >> 16);
        int pos = pos0 + ((emid < r) ? 1 : 0);
        if (n > 1) {                            // rare per-lane fixup
            for (int j = 1; j < n; ++j)
                pos += (s_mid[pos0 + j] < r) ? 1 : 0;
        }
        sv[k] = (float)pos;
        yv[k] = s_cb[pos] + m;
    }

    f32x4 sy0 = { sv[0], sv[1], sv[2], sv[3] };
    f32x4 yh0 = { yv[0], yv[1], yv[2], yv[3] };
    f32x4 sy1 = { sv[4], sv[5], sv[6], sv[7] };
    f32x4 yh1 = { yv[4], yv[5], yv[6], yv[7] };

    if (full) {
        __builtin_nontemporal_store(sy0, &sym_out[base]);
        __builtin_nontemporal_store(yh0, &yhat_out[base]);
        __builtin_nontemporal_store(sy1, &sym_out[base + 256]);
        __builtin_nontemporal_store(yh1, &yhat_out[base + 256]);
    } else {
        if (base < n4) {
            __builtin_nontemporal_store(sy0, &sym_out[base]);
            __builtin_nontemporal_store(yh0, &yhat_out[base]);
        }
        if (base + 256 < n4) {
            __builtin_nontemporal_store(sy1, &sym_out[base + 256]);
            __builtin_nontemporal_store(yh1, &yhat_out[base + 256]);
        }
    }
}

extern "C" void kernel_launch(void* const* d_in, const int* in_sizes, int n_in,
                              void* d_out, int out_size, void* d_ws, size_t ws_size,
                              hipStream_t stream)
{
    const float* x     = (const float*)d_in[0];
    const float* means = (const float*)d_in[1];
    const float* cb    = (const float*)d_in[2];

    const int n  = in_sizes[0];      // 25,165,824
    const int n4 = n / 4;            // 6,291,456 (divisible)

    float* out = (float*)d_out;      // [0..n): symbols (as float), [n..2n): y_hat

    // workspace layout: mid f32[64] | emid f32[1024] | epos u32[1024]
    float*        ws_mid  = (float*)d_ws;
    float*        ws_emid = (float*)((char*)d_ws + 256);
    unsigned int* ws_epos = (unsigned int*)((char*)d_ws + 256 + 4096);

    build_lut_kernel<<<1, 256, 0, stream>>>(cb, ws_mid, ws_emid, ws_epos);

    const int block = 256;
    const int grid  = (n4 + 511) / 512;   // 12288: flat grid, quick retire
    quant_dequant_kernel<<<grid, block, 0, stream>>>(
        (const float4*)x, (const float4*)means, cb,
        ws_mid, (const float4*)ws_emid, (const uint4*)ws_epos,
        (f32x4*)out, (f32x4*)(out + n), n4);
}